// Round 14
// baseline (562.664 us; speedup 1.0000x reference)
//
#include <hip/hip_runtime.h>

#define NN 50000
#define EE 800000
#define GG 128
#define LL 4
#define SCAN_B 196   // ceil(50048/256)

typedef __bf16 bf16x8 __attribute__((ext_vector_type(8)));
typedef __bf16 bf16x4 __attribute__((ext_vector_type(4)));
typedef float  f32x4  __attribute__((ext_vector_type(4)));

// fast silu: x * rcp(1 + 2^(-x*log2e))
__device__ __forceinline__ float silu_f(float x){
    float t = __builtin_amdgcn_exp2f(-1.44269504f * x);
    return x * __builtin_amdgcn_rcpf(1.0f + t);
}

// ---- pack 64x64 f32 weight blocks into MFMA B-fragment order (bf16) ----
__global__ __launch_bounds__(256) void pack_k(
        const float* __restrict__ msgW1, const float* __restrict__ msgW2,
        const float* __restrict__ updW1, const float* __restrict__ updW2,
        const float* __restrict__ outW1, const float* __restrict__ outW2,
        const float* __restrict__ W_in, __bf16* __restrict__ pk){
    int m = blockIdx.x;            // 0..22
    const float* src;
    if(m<20){
        int l=m/5, r=m%5;
        if(r==0)      src = msgW1 + (size_t)l*129*64;
        else if(r==1) src = msgW1 + (size_t)l*129*64 + 64*64;
        else if(r==2) src = msgW2 + (size_t)l*64*64;
        else if(r==3) src = updW1 + (size_t)l*64*64;
        else          src = updW2 + (size_t)l*64*64;
    } else if(m==20) src=outW1; else if(m==21) src=outW2; else src=W_in;
    __bf16* dst = pk + (size_t)m*4096;
    int tid=threadIdx.x;
    #pragma unroll
    for(int i=0;i<16;++i){
        int idx = tid*16+i;
        int frag = idx>>9, lane=(idx>>3)&63, j=idx&7;
        int s=frag>>2, ng=frag&3, q=lane>>4, nn=lane&15;
        dst[idx] = (__bf16)src[(32*s+8*q+j)*64 + 16*ng + nn];
    }
}
__device__ __forceinline__ bf16x8 ldfrag(const __bf16* pk, int s, int ng, int lane){
    return *(const bf16x8*)&pk[(((s*4+ng)*64 + lane))*8];
}

// ---- input MLP via MFMA with fused XY(layer 0): f = silu(x@W_in+b);
//      XY = [f@msgW1[0:64] | f@msgW1[64:128] + msgb1] ----
__global__ __launch_bounds__(256) void input_mfma(const float* __restrict__ x,
        const __bf16* __restrict__ pkW, const float* __restrict__ bg,
        const __bf16* __restrict__ pkXYa, const __bf16* __restrict__ pkXYb,
        const float* __restrict__ bXY,
        float* __restrict__ f, __bf16* __restrict__ XYout, int N){
    int tid=threadIdx.x, wid=tid>>6, lane=tid&63;
    int q=lane>>4, nn=lane&15;
    bf16x8 Bf[2][4];
    #pragma unroll
    for(int s=0;s<2;++s)
        #pragma unroll
        for(int ng=0;ng<4;++ng) Bf[s][ng]=ldfrag(pkW,s,ng,lane);
    float bias[4], bXYv[4];
    #pragma unroll
    for(int ng=0;ng<4;++ng){ bias[ng]=bg[16*ng+nn]; bXYv[ng]=bXY[16*ng+nn]; }

    __shared__ __align__(16) __bf16 sh1[4][16][72];

    int ntiles=(N+15)/16;
    int gw=gridDim.x*4;
    for(int t=blockIdx.x*4+wid; t<ntiles; t+=gw){
        int m=t*16+nn; int mc=(m<N)?m:(N-1);
        float4 a0=*(const float4*)&x[(size_t)mc*64 + 8*q];
        float4 a1=*(const float4*)&x[(size_t)mc*64 + 8*q + 4];
        float4 a2=*(const float4*)&x[(size_t)mc*64 + 32 + 8*q];
        float4 a3=*(const float4*)&x[(size_t)mc*64 + 32 + 8*q + 4];
        bf16x8 af0, af1;
        af0[0]=(__bf16)a0.x; af0[1]=(__bf16)a0.y; af0[2]=(__bf16)a0.z; af0[3]=(__bf16)a0.w;
        af0[4]=(__bf16)a1.x; af0[5]=(__bf16)a1.y; af0[6]=(__bf16)a1.z; af0[7]=(__bf16)a1.w;
        af1[0]=(__bf16)a2.x; af1[1]=(__bf16)a2.y; af1[2]=(__bf16)a2.z; af1[3]=(__bf16)a2.w;
        af1[4]=(__bf16)a3.x; af1[5]=(__bf16)a3.y; af1[6]=(__bf16)a3.z; af1[7]=(__bf16)a3.w;
        #pragma unroll
        for(int ng=0;ng<4;++ng){
            f32x4 acc; acc[0]=bias[ng]; acc[1]=bias[ng]; acc[2]=bias[ng]; acc[3]=bias[ng];
            acc=__builtin_amdgcn_mfma_f32_16x16x32_bf16(af0,Bf[0][ng],acc,0,0,0);
            acc=__builtin_amdgcn_mfma_f32_16x16x32_bf16(af1,Bf[1][ng],acc,0,0,0);
            #pragma unroll
            for(int r=0;r<4;++r){
                int row=t*16+4*q+r;
                float o=silu_f(acc[r]);
                if(row<N) f[(size_t)row*64+16*ng+nn]=o;
                sh1[wid][4*q+r][16*ng+nn]=(__bf16)o;
            }
        }
        asm volatile("" ::: "memory");
        bf16x8 a30=*(const bf16x8*)&sh1[wid][nn][8*q];
        bf16x8 a31=*(const bf16x8*)&sh1[wid][nn][32+8*q];
        #pragma unroll
        for(int ng=0;ng<8;++ng){
            const __bf16* pkx = (ng<4)? pkXYa : pkXYb;
            int g2 = ng&3;
            float bb = (ng<4)?0.f:bXYv[ng-4];
            f32x4 accx; accx[0]=bb; accx[1]=bb; accx[2]=bb; accx[3]=bb;
            accx=__builtin_amdgcn_mfma_f32_16x16x32_bf16(a30,ldfrag(pkx,0,g2,lane),accx,0,0,0);
            accx=__builtin_amdgcn_mfma_f32_16x16x32_bf16(a31,ldfrag(pkx,1,g2,lane),accx,0,0,0);
            #pragma unroll
            for(int r=0;r<4;++r){
                int row=t*16+4*q+r;
                if(row<N) XYout[(size_t)row*128 + 16*ng + nn]=(__bf16)accx[r];
            }
        }
        asm volatile("" ::: "memory");
    }
}

__global__ void hist_k(const int* __restrict__ dst, int* __restrict__ deg, int E){
    int e=blockIdx.x*blockDim.x+threadIdx.x;
    if(e<E) atomicAdd(&deg[dst[e]],1);
}

// ---- 3-pass parallel exclusive scan ----
__global__ __launch_bounds__(256) void scan1_k(const int* __restrict__ deg, int* __restrict__ curs,
        int* __restrict__ bsum, int N){
    __shared__ int sv[256];
    int tid=threadIdx.x;
    int idx=blockIdx.x*256+tid;
    int v=(idx<N)?deg[idx]:0;
    sv[tid]=v; __syncthreads();
    #pragma unroll
    for(int off=1; off<256; off<<=1){
        int a=(tid>=off)?sv[tid-off]:0;
        __syncthreads(); sv[tid]+=a; __syncthreads();
    }
    if(idx<N) curs[idx]=sv[tid]-v;
    if(tid==255) bsum[blockIdx.x]=sv[255];
}
__global__ __launch_bounds__(256) void scan2_k(int* __restrict__ bsum, int B){
    __shared__ int sv[256];
    int tid=threadIdx.x;
    int v=(tid<B)?bsum[tid]:0;
    sv[tid]=v; __syncthreads();
    #pragma unroll
    for(int off=1; off<256; off<<=1){
        int a=(tid>=off)?sv[tid-off]:0;
        __syncthreads(); sv[tid]+=a; __syncthreads();
    }
    if(tid<B) bsum[tid]=sv[tid]-v;
}
__global__ __launch_bounds__(256) void scan3_k(int* __restrict__ curs, const int* __restrict__ bsum, int N){
    int idx=blockIdx.x*256+threadIdx.x;
    if(idx<N) curs[idx]+=bsum[blockIdx.x];
}

// rank-scatter: slot-ordered packed metadata {src, dst, w^2}
__global__ void fill_k(const int* __restrict__ src, const int* __restrict__ dst,
                       const float* __restrict__ w, int* __restrict__ cursor,
                       int4* __restrict__ meta, int E){
    int e=blockIdx.x*blockDim.x+threadIdx.x;
    if(e<E){
        int d=dst[e];
        int r=atomicAdd(&cursor[d],1);
        float ww=w[e];
        int4 v; v.x=src[e]; v.y=d; v.z=__float_as_int(ww*ww); v.w=0;
        meta[r]=v;
    }
}

// edge kernel v6: phase-reordered pipeline, meta prefetch at distance 2,
// ballot/bitmask scatter, swizzled b64 sm writes. (unchanged)
__global__ __launch_bounds__(256) void edge_mfma6(
        const __bf16* __restrict__ XY, const int4* __restrict__ meta,
        const __bf16* __restrict__ pkW2,
        const float* __restrict__ W1, const float* __restrict__ b2,
        float* __restrict__ msum, int E){
    int tid=threadIdx.x, wid=tid>>6, lane=tid&63;
    int q=lane>>4, nn=lane&15;

    bf16x8 B2f[2][4];
    #pragma unroll
    for(int s=0;s<2;++s)
        #pragma unroll
        for(int ng=0;ng<4;++ng) B2f[s][ng]=ldfrag(pkW2,s,ng,lane);
    float w128lo[8], w128hi[8];
    #pragma unroll
    for(int j=0;j<8;++j){
        w128lo[j]=W1[128*64 + 8*q+j];
        w128hi[j]=W1[128*64 + 32+8*q+j];
    }
    float bias2[4];
    #pragma unroll
    for(int ng=0;ng<4;++ng) bias2[ng]=b2[16*ng+nn];

    __shared__ __align__(16) __bf16 sm16[4][32][68];
    int cpos = 4*(lane&15) + (lane>>4);

    int ntiles=E/32;
    int nw=gridDim.x*4;
    int chunk=(ntiles+nw-1)/nw;
    int wgl=blockIdx.x*4+wid;
    int t0=wgl*chunk, t1=t0+chunk; if(t1>ntiles) t1=ntiles;
    if(t0>=t1) return;

    int4 mv  = meta[(size_t)t0*32 + (lane&31)];
    int4 mvn = (t0+1<t1) ? meta[(size_t)(t0+1)*32 + (lane&31)] : mv;
    bf16x8 gx0lo,gx0hi,gy0lo,gy0hi,gx1lo,gx1hi,gy1lo,gy1hi;
    {
        int se0=__shfl(mv.x, nn,64),    de0=__shfl(mv.y, nn,64);
        int se1=__shfl(mv.x, 16+nn,64), de1=__shfl(mv.y, 16+nn,64);
        const __bf16* xp0=XY+(size_t)se0*128; const __bf16* yp0=XY+(size_t)de0*128+64;
        const __bf16* xp1=XY+(size_t)se1*128; const __bf16* yp1=XY+(size_t)de1*128+64;
        gx0lo=*(const bf16x8*)(xp0+8*q); gx0hi=*(const bf16x8*)(xp0+32+8*q);
        gy0lo=*(const bf16x8*)(yp0+8*q); gy0hi=*(const bf16x8*)(yp0+32+8*q);
        gx1lo=*(const bf16x8*)(xp1+8*q); gx1hi=*(const bf16x8*)(xp1+32+8*q);
        gy1lo=*(const bf16x8*)(yp1+8*q); gy1hi=*(const bf16x8*)(yp1+32+8*q);
    }
    int cur=__builtin_amdgcn_readlane(mv.y, 0);
    float vsum=0.f;

    for(int t=t0;t<t1;++t){
        int4 mv2 = mvn;
        if(t+2<t1) mv2 = meta[(size_t)(t+2)*32 + (lane&31)];

        int d_ = mv.y;
        float w2v = __int_as_float(mv.z);

        bf16x8 A0lo,A0hi,A1lo,A1hi;
        {
            float w2a = __shfl(w2v, nn, 64);
            float w2b = __shfl(w2v, 16+nn, 64);
            #pragma unroll
            for(int j=0;j<8;++j){
                A0lo[j]=(__bf16)silu_f((float)gx0lo[j] + (float)gy0lo[j] + w2a*w128lo[j]);
                A0hi[j]=(__bf16)silu_f((float)gx0hi[j] + (float)gy0hi[j] + w2a*w128hi[j]);
                A1lo[j]=(__bf16)silu_f((float)gx1lo[j] + (float)gy1lo[j] + w2b*w128lo[j]);
                A1hi[j]=(__bf16)silu_f((float)gx1hi[j] + (float)gy1hi[j] + w2b*w128hi[j]);
            }
        }
        if(t+1<t1){
            int se0=__shfl(mvn.x, nn,64),    de0=__shfl(mvn.y, nn,64);
            int se1=__shfl(mvn.x, 16+nn,64), de1=__shfl(mvn.y, 16+nn,64);
            const __bf16* xp0=XY+(size_t)se0*128; const __bf16* yp0=XY+(size_t)de0*128+64;
            const __bf16* xp1=XY+(size_t)se1*128; const __bf16* yp1=XY+(size_t)de1*128+64;
            gx0lo=*(const bf16x8*)(xp0+8*q); gx0hi=*(const bf16x8*)(xp0+32+8*q);
            gy0lo=*(const bf16x8*)(yp0+8*q); gy0hi=*(const bf16x8*)(yp0+32+8*q);
            gx1lo=*(const bf16x8*)(xp1+8*q); gx1hi=*(const bf16x8*)(xp1+32+8*q);
            gy1lo=*(const bf16x8*)(yp1+8*q); gy1hi=*(const bf16x8*)(yp1+32+8*q);
        }
        #pragma unroll
        for(int h=0;h<2;++h){
            bf16x8 alo = h ? A1lo : A0lo;
            bf16x8 ahi = h ? A1hi : A0hi;
            f32x4 acc2[4];
            #pragma unroll
            for(int ng=0;ng<4;++ng){ f32x4 c; c[0]=bias2[ng]; c[1]=bias2[ng]; c[2]=bias2[ng]; c[3]=bias2[ng]; acc2[ng]=c; }
            #pragma unroll
            for(int ng=0;ng<4;++ng){
                acc2[ng]=__builtin_amdgcn_mfma_f32_16x16x32_bf16(alo,B2f[0][ng],acc2[ng],0,0,0);
                acc2[ng]=__builtin_amdgcn_mfma_f32_16x16x32_bf16(ahi,B2f[1][ng],acc2[ng],0,0,0);
            }
            #pragma unroll
            for(int r=0;r<4;++r){
                bf16x4 pv;
                #pragma unroll
                for(int ng=0;ng<4;++ng) pv[ng]=(__bf16)silu_f(silu_f(acc2[ng][r]));
                *(bf16x4*)&sm16[wid][16*h+4*q+r][4*nn] = pv;
            }
        }
        asm volatile("" ::: "memory");
        {
            int dprev = __shfl(d_, (lane+63)&63, 64);
            unsigned long long bal = __ballot(lane>=1 && lane<32 && d_!=dprev);
            unsigned bmask = (unsigned)bal;
            int d0 = __builtin_amdgcn_readlane(d_, 0);
            if(d0 != cur) bmask |= 1u;
            #pragma unroll
            for(int r=0;r<32;++r){
                if(bmask & (1u<<r)){
                    atomicAdd(&msum[(size_t)cur*64+lane], vsum);
                    vsum=0.f;
                    cur=__builtin_amdgcn_readlane(d_, r);
                }
                vsum += (float)sm16[wid][r][cpos];
            }
        }
        asm volatile("" ::: "memory");
        mv = mvn; mvn = mv2;
    }
    atomicAdd(&msum[(size_t)cur*64+lane], vsum);
}

// node 2-layer MLP via MFMA with optional fused next-layer XY (unchanged)
__global__ __launch_bounds__(256) void node_mfma(float* A, const float* F,
        const __bf16* __restrict__ pkW1, const float* __restrict__ b1,
        const __bf16* __restrict__ pkW2, const float* __restrict__ b2,
        float* __restrict__ out, int zeroA,
        const __bf16* __restrict__ pkXYa, const __bf16* __restrict__ pkXYb,
        const float* __restrict__ bXY, __bf16* __restrict__ XYout, int N){
    int tid=threadIdx.x, wid=tid>>6, lane=tid&63;
    int q=lane>>4, nn=lane&15;

    bf16x8 B1f[2][4], B2f[2][4];
    #pragma unroll
    for(int s=0;s<2;++s)
        #pragma unroll
        for(int ng=0;ng<4;++ng){ B1f[s][ng]=ldfrag(pkW1,s,ng,lane); B2f[s][ng]=ldfrag(pkW2,s,ng,lane); }
    float bias1[4], bias2[4];
    #pragma unroll
    for(int ng=0;ng<4;++ng){ bias1[ng]=b1[16*ng+nn]; bias2[ng]=b2[16*ng+nn]; }
    bool hasXY = (pkXYa != nullptr);
    float bXYv[4];
    #pragma unroll
    for(int j=0;j<4;++j) bXYv[j] = hasXY ? bXY[16*j+nn] : 0.f;

    __shared__ __align__(16) __bf16 sh1[4][16][72];
    __shared__ __align__(16) float sF[4][16][68];
    bool hasF = (F != nullptr);

    int ntiles=(N+15)/16;
    int gw=gridDim.x*4;
    for(int t=blockIdx.x*4+wid; t<ntiles; t+=gw){
        int m=t*16+nn;
        int mc=(m<N)?m:(N-1);
        float4 a0=*(const float4*)&A[(size_t)mc*64 + 8*q];
        float4 a1=*(const float4*)&A[(size_t)mc*64 + 8*q + 4];
        float4 a2=*(const float4*)&A[(size_t)mc*64 + 32 + 8*q];
        float4 a3=*(const float4*)&A[(size_t)mc*64 + 32 + 8*q + 4];
        if(hasF){
            float4 f0=*(const float4*)&F[(size_t)mc*64 + 8*q];
            float4 f1=*(const float4*)&F[(size_t)mc*64 + 8*q + 4];
            float4 f2_=*(const float4*)&F[(size_t)mc*64 + 32 + 8*q];
            float4 f3=*(const float4*)&F[(size_t)mc*64 + 32 + 8*q + 4];
            a0.x+=f0.x; a0.y+=f0.y; a0.z+=f0.z; a0.w+=f0.w;
            a1.x+=f1.x; a1.y+=f1.y; a1.z+=f1.z; a1.w+=f1.w;
            a2.x+=f2_.x; a2.y+=f2_.y; a2.z+=f2_.z; a2.w+=f2_.w;
            a3.x+=f3.x; a3.y+=f3.y; a3.z+=f3.z; a3.w+=f3.w;
            *(float4*)&sF[wid][nn][8*q]   = f0;
            *(float4*)&sF[wid][nn][8*q+4] = f1;
            *(float4*)&sF[wid][nn][32+8*q]   = f2_;
            *(float4*)&sF[wid][nn][32+8*q+4] = f3;
        }
        if(zeroA && m<N){
            float4 z; z.x=0.f; z.y=0.f; z.z=0.f; z.w=0.f;
            *(float4*)&A[(size_t)mc*64 + 8*q]      = z;
            *(float4*)&A[(size_t)mc*64 + 8*q + 4]  = z;
            *(float4*)&A[(size_t)mc*64 + 32 + 8*q] = z;
            *(float4*)&A[(size_t)mc*64 + 32 + 8*q + 4] = z;
        }
        bf16x8 af0, af1;
        af0[0]=(__bf16)a0.x; af0[1]=(__bf16)a0.y; af0[2]=(__bf16)a0.z; af0[3]=(__bf16)a0.w;
        af0[4]=(__bf16)a1.x; af0[5]=(__bf16)a1.y; af0[6]=(__bf16)a1.z; af0[7]=(__bf16)a1.w;
        af1[0]=(__bf16)a2.x; af1[1]=(__bf16)a2.y; af1[2]=(__bf16)a2.z; af1[3]=(__bf16)a2.w;
        af1[4]=(__bf16)a3.x; af1[5]=(__bf16)a3.y; af1[6]=(__bf16)a3.z; af1[7]=(__bf16)a3.w;

        f32x4 acc[4];
        #pragma unroll
        for(int ng=0;ng<4;++ng){ f32x4 c; c[0]=bias1[ng]; c[1]=bias1[ng]; c[2]=bias1[ng]; c[3]=bias1[ng]; acc[ng]=c; }
        #pragma unroll
        for(int ng=0;ng<4;++ng){
            acc[ng]=__builtin_amdgcn_mfma_f32_16x16x32_bf16(af0,B1f[0][ng],acc[ng],0,0,0);
            acc[ng]=__builtin_amdgcn_mfma_f32_16x16x32_bf16(af1,B1f[1][ng],acc[ng],0,0,0);
        }
        #pragma unroll
        for(int ng=0;ng<4;++ng)
            #pragma unroll
            for(int r=0;r<4;++r)
                sh1[wid][4*q+r][16*ng+nn]=(__bf16)silu_f(acc[ng][r]);
        asm volatile("" ::: "memory");
        bf16x8 a20=*(const bf16x8*)&sh1[wid][nn][8*q];
        bf16x8 a21=*(const bf16x8*)&sh1[wid][nn][32+8*q];
        f32x4 acc2[4];
        #pragma unroll
        for(int ng=0;ng<4;++ng){ f32x4 c; c[0]=bias2[ng]; c[1]=bias2[ng]; c[2]=bias2[ng]; c[3]=bias2[ng]; acc2[ng]=c; }
        #pragma unroll
        for(int ng=0;ng<4;++ng){
            acc2[ng]=__builtin_amdgcn_mfma_f32_16x16x32_bf16(a20,B2f[0][ng],acc2[ng],0,0,0);
            acc2[ng]=__builtin_amdgcn_mfma_f32_16x16x32_bf16(a21,B2f[1][ng],acc2[ng],0,0,0);
        }
        #pragma unroll
        for(int ng=0;ng<4;++ng)
            #pragma unroll
            for(int r=0;r<4;++r){
                int row=t*16+4*q+r;
                float o=acc2[ng][r];
                if(hasF) o += sF[wid][4*q+r][16*ng+nn];
                if(row<N) out[(size_t)row*64 + 16*ng + nn]=o;
                if(hasXY) sh1[wid][4*q+r][16*ng+nn]=(__bf16)o;
            }
        asm volatile("" ::: "memory");
        if(hasXY){
            bf16x8 a30=*(const bf16x8*)&sh1[wid][nn][8*q];
            bf16x8 a31=*(const bf16x8*)&sh1[wid][nn][32+8*q];
            #pragma unroll
            for(int ng=0;ng<8;++ng){
                const __bf16* pkx = (ng<4)? pkXYa : pkXYb;
                int g2 = ng&3;
                float bb = (ng<4)?0.f:bXYv[ng-4];
                f32x4 accx; accx[0]=bb; accx[1]=bb; accx[2]=bb; accx[3]=bb;
                accx=__builtin_amdgcn_mfma_f32_16x16x32_bf16(a30,ldfrag(pkx,0,g2,lane),accx,0,0,0);
                accx=__builtin_amdgcn_mfma_f32_16x16x32_bf16(a31,ldfrag(pkx,1,g2,lane),accx,0,0,0);
                #pragma unroll
                for(int r=0;r<4;++r){
                    int row=t*16+4*q+r;
                    if(row<N) XYout[(size_t)row*128 + 16*ng + nn]=(__bf16)accx[r];
                }
            }
        }
        asm volatile("" ::: "memory");
    }
}

// fused per-graph reduce (sorted gid, binary-searched ranges, zero atomics) + readout MLP
__global__ __launch_bounds__(256) void readout_fused(const float* __restrict__ f2,
        const int* __restrict__ gid,
        const float* __restrict__ W1, const float* __restrict__ b1,
        const float* __restrict__ W2, const float* __restrict__ b2,
        float* __restrict__ out, int N, int G){
    __shared__ __align__(16) float sr[4][192];
    int tid=threadIdx.x, wid=tid>>6, lane=tid&63;
    int g=blockIdx.x*4+wid;
    if(g<G){
        // node range [n0, n1) for graph g in sorted gid
        int lo=0, hi=N;
        while(lo<hi){ int mid=(lo+hi)>>1; if(gid[mid]<g) lo=mid+1; else hi=mid; }
        int a=lo, b=N;
        while(a<b){ int mid=(a+b)>>1; if(gid[mid]<g+1) a=mid+1; else b=mid; }
        int n0=lo, n1=a;
        float s=0.f, mx=-__builtin_inff();
        int n=n0;
        for(; n+4<=n1; n+=4){
            float v0=f2[(size_t)(n+0)*64+lane];
            float v1=f2[(size_t)(n+1)*64+lane];
            float v2=f2[(size_t)(n+2)*64+lane];
            float v3=f2[(size_t)(n+3)*64+lane];
            s += (v0+v1)+(v2+v3);
            mx = fmaxf(mx, fmaxf(fmaxf(v0,v1), fmaxf(v2,v3)));
        }
        for(; n<n1; ++n){ float v=f2[(size_t)n*64+lane]; s+=v; mx=fmaxf(mx,v); }
        float c=(float)(n1-n0);
        float mean=s/fmaxf(c,1.0f);
        sr[wid][lane]=s; sr[wid][64+lane]=mean; sr[wid][128+lane]=mx;
    }
    __syncthreads();
    if(g<G){
        float h=b1[lane];
        for(int k=0;k<192;k+=4){
            float4 r4=*(const float4*)&sr[wid][k];
            h += r4.x*W1[(k+0)*64+lane] + r4.y*W1[(k+1)*64+lane]
               + r4.z*W1[(k+2)*64+lane] + r4.w*W1[(k+3)*64+lane];
        }
        h=silu_f(h);
        float p=h*W2[lane];
        #pragma unroll
        for(int off=32;off>0;off>>=1) p += __shfl_down(p, off, 64);
        if(lane==0) out[g]=p+b2[0];
    }
}

extern "C" void kernel_launch(void* const* d_in, const int* in_sizes, int n_in,
                              void* d_out, int out_size, void* d_ws, size_t ws_size,
                              hipStream_t stream){
    const float* x     = (const float*)d_in[0];
    const float* w     = (const float*)d_in[1];
    const int*   src   = (const int*)d_in[2];
    const int*   dst   = (const int*)d_in[3];
    const int*   gid   = (const int*)d_in[4];
    const float* W_in  = (const float*)d_in[5];
    const float* b_in  = (const float*)d_in[6];
    const float* msgW1 = (const float*)d_in[7];
    const float* msgb1 = (const float*)d_in[8];
    const float* msgW2 = (const float*)d_in[9];
    const float* msgb2 = (const float*)d_in[10];
    const float* updW1 = (const float*)d_in[11];
    const float* updb1 = (const float*)d_in[12];
    const float* updW2 = (const float*)d_in[13];
    const float* updb2 = (const float*)d_in[14];
    const float* outW1 = (const float*)d_in[15];
    const float* outb1 = (const float*)d_in[16];
    const float* outW2 = (const float*)d_in[17];
    const float* outb2 = (const float*)d_in[18];
    const float* roW1  = (const float*)d_in[19];
    const float* rob1  = (const float*)d_in[20];
    const float* roW2  = (const float*)d_in[21];
    const float* rob2  = (const float*)d_in[22];

    float*  f     = (float*)d_ws;                         // N*64 f32
    float*  msum  = f + (size_t)NN*64;                    // N*64 f32 (reused as f2)
    float*  f2    = msum;
    __bf16* XY    = (__bf16*)(msum + (size_t)NN*64);      // N*128 bf16
    int4*   meta  = (int4*)(XY + (size_t)NN*128);         // E (16B each)
    __bf16* pk    = (__bf16*)(meta + EE);                 // 23*4096 bf16
    int*    deg   = (int*)(pk + 23*4096);                 // N (padded)
    int*    curs  = deg + 50048;                          // N (padded)
    int*    bsum  = curs + 50048;                         // SCAN_B (padded 256)

    pack_k<<<dim3(23),dim3(256),0,stream>>>(msgW1, msgW2, updW1, updW2, outW1, outW2, W_in, pk);

    hipMemsetAsync(deg, 0, 50048*sizeof(int), stream);
    hist_k<<<dim3((EE+255)/256),dim3(256),0,stream>>>(dst, deg, EE);
    scan1_k<<<dim3(SCAN_B),dim3(256),0,stream>>>(deg, curs, bsum, NN);
    scan2_k<<<dim3(1),dim3(256),0,stream>>>(bsum, SCAN_B);
    scan3_k<<<dim3(SCAN_B),dim3(256),0,stream>>>(curs, bsum, NN);
    fill_k<<<dim3((EE+255)/256),dim3(256),0,stream>>>(src, dst, w, curs, meta, EE);

    // msum zeroed once here; node_mfma (zeroA=1) re-zeros it for each subsequent layer
    hipMemsetAsync(msum, 0, (size_t)NN*64*sizeof(float), stream);
    // input MLP with fused XY(layer 0)
    input_mfma<<<dim3(782),dim3(256),0,stream>>>(x, pk + (size_t)22*4096, b_in,
        pk + (size_t)0*4096, pk + (size_t)1*4096, msgb1 + 0*64, f, XY, NN);
    for(int l=0;l<LL;++l){
        edge_mfma6<<<dim3(1280),dim3(256),0,stream>>>(XY, meta,
            pk + (size_t)(5*l+2)*4096,
            msgW1 + (size_t)l*129*64, msgb2 + l*64, msum, EE);
        bool fuse = (l < LL-1);
        node_mfma<<<dim3(782),dim3(256),0,stream>>>(msum, f,
            pk + (size_t)(5*l+3)*4096, updb1 + l*64,
            pk + (size_t)(5*l+4)*4096, updb2 + l*64, f, 1,
            fuse ? pk + (size_t)(5*(l+1)+0)*4096 : nullptr,
            fuse ? pk + (size_t)(5*(l+1)+1)*4096 : nullptr,
            fuse ? msgb1 + (l+1)*64 : nullptr,
            XY, NN);
    }
    node_mfma<<<dim3(782),dim3(256),0,stream>>>(f, nullptr,
        pk + (size_t)20*4096, outb1, pk + (size_t)21*4096, outb2, f2, 0,
        nullptr, nullptr, nullptr, nullptr, NN);
    readout_fused<<<dim3(32),dim3(256),0,stream>>>(f2, gid, roW1, rob1, roW2, rob2,
        (float*)d_out, NN, GG);
}

// Round 15
// 538.000 us; speedup vs baseline: 1.0458x; 1.0458x over previous
//
#include <hip/hip_runtime.h>

#define NN 50000
#define EE 800000
#define GG 128
#define LL 4
#define SCAN_B 196   // ceil(50048/256)

typedef __bf16 bf16x8 __attribute__((ext_vector_type(8)));
typedef __bf16 bf16x4 __attribute__((ext_vector_type(4)));
typedef float  f32x4  __attribute__((ext_vector_type(4)));

// fast silu: x * rcp(1 + 2^(-x*log2e))
__device__ __forceinline__ float silu_f(float x){
    float t = __builtin_amdgcn_exp2f(-1.44269504f * x);
    return x * __builtin_amdgcn_rcpf(1.0f + t);
}
__device__ __forceinline__ unsigned fenc(float v){
    unsigned u = __float_as_uint(v);
    return (u & 0x80000000u) ? ~u : (u | 0x80000000u);
}
__device__ __forceinline__ float fdec(unsigned u){
    return (u & 0x80000000u) ? __uint_as_float(u & 0x7fffffffu) : __uint_as_float(~u);
}

// ---- pack 64x64 f32 weight blocks into MFMA B-fragment order (bf16) ----
__global__ __launch_bounds__(256) void pack_k(
        const float* __restrict__ msgW1, const float* __restrict__ msgW2,
        const float* __restrict__ updW1, const float* __restrict__ updW2,
        const float* __restrict__ outW1, const float* __restrict__ outW2,
        const float* __restrict__ W_in, __bf16* __restrict__ pk){
    int m = blockIdx.x;            // 0..22
    const float* src;
    if(m<20){
        int l=m/5, r=m%5;
        if(r==0)      src = msgW1 + (size_t)l*129*64;
        else if(r==1) src = msgW1 + (size_t)l*129*64 + 64*64;
        else if(r==2) src = msgW2 + (size_t)l*64*64;
        else if(r==3) src = updW1 + (size_t)l*64*64;
        else          src = updW2 + (size_t)l*64*64;
    } else if(m==20) src=outW1; else if(m==21) src=outW2; else src=W_in;
    __bf16* dst = pk + (size_t)m*4096;
    int tid=threadIdx.x;
    #pragma unroll
    for(int i=0;i<16;++i){
        int idx = tid*16+i;
        int frag = idx>>9, lane=(idx>>3)&63, j=idx&7;
        int s=frag>>2, ng=frag&3, q=lane>>4, nn=lane&15;
        dst[idx] = (__bf16)src[(32*s+8*q+j)*64 + 16*ng + nn];
    }
}
__device__ __forceinline__ bf16x8 ldfrag(const __bf16* pk, int s, int ng, int lane){
    return *(const bf16x8*)&pk[(((s*4+ng)*64 + lane))*8];
}

// ---- input MLP via MFMA with fused XY(layer 0) ----
__global__ __launch_bounds__(256) void input_mfma(const float* __restrict__ x,
        const __bf16* __restrict__ pkW, const float* __restrict__ bg,
        const __bf16* __restrict__ pkXYa, const __bf16* __restrict__ pkXYb,
        const float* __restrict__ bXY,
        float* __restrict__ f, __bf16* __restrict__ XYout, int N){
    int tid=threadIdx.x, wid=tid>>6, lane=tid&63;
    int q=lane>>4, nn=lane&15;
    bf16x8 Bf[2][4];
    #pragma unroll
    for(int s=0;s<2;++s)
        #pragma unroll
        for(int ng=0;ng<4;++ng) Bf[s][ng]=ldfrag(pkW,s,ng,lane);
    float bias[4], bXYv[4];
    #pragma unroll
    for(int ng=0;ng<4;++ng){ bias[ng]=bg[16*ng+nn]; bXYv[ng]=bXY[16*ng+nn]; }

    __shared__ __align__(16) __bf16 sh1[4][16][72];

    int ntiles=(N+15)/16;
    int gw=gridDim.x*4;
    for(int t=blockIdx.x*4+wid; t<ntiles; t+=gw){
        int m=t*16+nn; int mc=(m<N)?m:(N-1);
        float4 a0=*(const float4*)&x[(size_t)mc*64 + 8*q];
        float4 a1=*(const float4*)&x[(size_t)mc*64 + 8*q + 4];
        float4 a2=*(const float4*)&x[(size_t)mc*64 + 32 + 8*q];
        float4 a3=*(const float4*)&x[(size_t)mc*64 + 32 + 8*q + 4];
        bf16x8 af0, af1;
        af0[0]=(__bf16)a0.x; af0[1]=(__bf16)a0.y; af0[2]=(__bf16)a0.z; af0[3]=(__bf16)a0.w;
        af0[4]=(__bf16)a1.x; af0[5]=(__bf16)a1.y; af0[6]=(__bf16)a1.z; af0[7]=(__bf16)a1.w;
        af1[0]=(__bf16)a2.x; af1[1]=(__bf16)a2.y; af1[2]=(__bf16)a2.z; af1[3]=(__bf16)a2.w;
        af1[4]=(__bf16)a3.x; af1[5]=(__bf16)a3.y; af1[6]=(__bf16)a3.z; af1[7]=(__bf16)a3.w;
        #pragma unroll
        for(int ng=0;ng<4;++ng){
            f32x4 acc; acc[0]=bias[ng]; acc[1]=bias[ng]; acc[2]=bias[ng]; acc[3]=bias[ng];
            acc=__builtin_amdgcn_mfma_f32_16x16x32_bf16(af0,Bf[0][ng],acc,0,0,0);
            acc=__builtin_amdgcn_mfma_f32_16x16x32_bf16(af1,Bf[1][ng],acc,0,0,0);
            #pragma unroll
            for(int r=0;r<4;++r){
                int row=t*16+4*q+r;
                float o=silu_f(acc[r]);
                if(row<N) f[(size_t)row*64+16*ng+nn]=o;
                sh1[wid][4*q+r][16*ng+nn]=(__bf16)o;
            }
        }
        asm volatile("" ::: "memory");
        bf16x8 a30=*(const bf16x8*)&sh1[wid][nn][8*q];
        bf16x8 a31=*(const bf16x8*)&sh1[wid][nn][32+8*q];
        #pragma unroll
        for(int ng=0;ng<8;++ng){
            const __bf16* pkx = (ng<4)? pkXYa : pkXYb;
            int g2 = ng&3;
            float bb = (ng<4)?0.f:bXYv[ng-4];
            f32x4 accx; accx[0]=bb; accx[1]=bb; accx[2]=bb; accx[3]=bb;
            accx=__builtin_amdgcn_mfma_f32_16x16x32_bf16(a30,ldfrag(pkx,0,g2,lane),accx,0,0,0);
            accx=__builtin_amdgcn_mfma_f32_16x16x32_bf16(a31,ldfrag(pkx,1,g2,lane),accx,0,0,0);
            #pragma unroll
            for(int r=0;r<4;++r){
                int row=t*16+4*q+r;
                if(row<N) XYout[(size_t)row*128 + 16*ng + nn]=(__bf16)accx[r];
            }
        }
        asm volatile("" ::: "memory");
    }
}

__global__ void hist_k(const int* __restrict__ dst, int* __restrict__ deg, int E){
    int e=blockIdx.x*blockDim.x+threadIdx.x;
    if(e<E) atomicAdd(&deg[dst[e]],1);
}

// ---- 3-pass parallel exclusive scan ----
__global__ __launch_bounds__(256) void scan1_k(const int* __restrict__ deg, int* __restrict__ curs,
        int* __restrict__ bsum, int N){
    __shared__ int sv[256];
    int tid=threadIdx.x;
    int idx=blockIdx.x*256+tid;
    int v=(idx<N)?deg[idx]:0;
    sv[tid]=v; __syncthreads();
    #pragma unroll
    for(int off=1; off<256; off<<=1){
        int a=(tid>=off)?sv[tid-off]:0;
        __syncthreads(); sv[tid]+=a; __syncthreads();
    }
    if(idx<N) curs[idx]=sv[tid]-v;
    if(tid==255) bsum[blockIdx.x]=sv[255];
}
__global__ __launch_bounds__(256) void scan2_k(int* __restrict__ bsum, int B){
    __shared__ int sv[256];
    int tid=threadIdx.x;
    int v=(tid<B)?bsum[tid]:0;
    sv[tid]=v; __syncthreads();
    #pragma unroll
    for(int off=1; off<256; off<<=1){
        int a=(tid>=off)?sv[tid-off]:0;
        __syncthreads(); sv[tid]+=a; __syncthreads();
    }
    if(tid<B) bsum[tid]=sv[tid]-v;
}
__global__ __launch_bounds__(256) void scan3_k(int* __restrict__ curs, const int* __restrict__ bsum, int N){
    int idx=blockIdx.x*256+threadIdx.x;
    if(idx<N) curs[idx]+=bsum[blockIdx.x];
}

// rank-scatter: slot-ordered packed metadata {src, dst, w^2}
__global__ void fill_k(const int* __restrict__ src, const int* __restrict__ dst,
                       const float* __restrict__ w, int* __restrict__ cursor,
                       int4* __restrict__ meta, int E){
    int e=blockIdx.x*blockDim.x+threadIdx.x;
    if(e<E){
        int d=dst[e];
        int r=atomicAdd(&cursor[d],1);
        float ww=w[e];
        int4 v; v.x=src[e]; v.y=d; v.z=__float_as_int(ww*ww); v.w=0;
        meta[r]=v;
    }
}

// edge kernel v6 (unchanged)
__global__ __launch_bounds__(256) void edge_mfma6(
        const __bf16* __restrict__ XY, const int4* __restrict__ meta,
        const __bf16* __restrict__ pkW2,
        const float* __restrict__ W1, const float* __restrict__ b2,
        float* __restrict__ msum, int E){
    int tid=threadIdx.x, wid=tid>>6, lane=tid&63;
    int q=lane>>4, nn=lane&15;

    bf16x8 B2f[2][4];
    #pragma unroll
    for(int s=0;s<2;++s)
        #pragma unroll
        for(int ng=0;ng<4;++ng) B2f[s][ng]=ldfrag(pkW2,s,ng,lane);
    float w128lo[8], w128hi[8];
    #pragma unroll
    for(int j=0;j<8;++j){
        w128lo[j]=W1[128*64 + 8*q+j];
        w128hi[j]=W1[128*64 + 32+8*q+j];
    }
    float bias2[4];
    #pragma unroll
    for(int ng=0;ng<4;++ng) bias2[ng]=b2[16*ng+nn];

    __shared__ __align__(16) __bf16 sm16[4][32][68];
    int cpos = 4*(lane&15) + (lane>>4);

    int ntiles=E/32;
    int nw=gridDim.x*4;
    int chunk=(ntiles+nw-1)/nw;
    int wgl=blockIdx.x*4+wid;
    int t0=wgl*chunk, t1=t0+chunk; if(t1>ntiles) t1=ntiles;
    if(t0>=t1) return;

    int4 mv  = meta[(size_t)t0*32 + (lane&31)];
    int4 mvn = (t0+1<t1) ? meta[(size_t)(t0+1)*32 + (lane&31)] : mv;
    bf16x8 gx0lo,gx0hi,gy0lo,gy0hi,gx1lo,gx1hi,gy1lo,gy1hi;
    {
        int se0=__shfl(mv.x, nn,64),    de0=__shfl(mv.y, nn,64);
        int se1=__shfl(mv.x, 16+nn,64), de1=__shfl(mv.y, 16+nn,64);
        const __bf16* xp0=XY+(size_t)se0*128; const __bf16* yp0=XY+(size_t)de0*128+64;
        const __bf16* xp1=XY+(size_t)se1*128; const __bf16* yp1=XY+(size_t)de1*128+64;
        gx0lo=*(const bf16x8*)(xp0+8*q); gx0hi=*(const bf16x8*)(xp0+32+8*q);
        gy0lo=*(const bf16x8*)(yp0+8*q); gy0hi=*(const bf16x8*)(yp0+32+8*q);
        gx1lo=*(const bf16x8*)(xp1+8*q); gx1hi=*(const bf16x8*)(xp1+32+8*q);
        gy1lo=*(const bf16x8*)(yp1+8*q); gy1hi=*(const bf16x8*)(yp1+32+8*q);
    }
    int cur=__builtin_amdgcn_readlane(mv.y, 0);
    float vsum=0.f;

    for(int t=t0;t<t1;++t){
        int4 mv2 = mvn;
        if(t+2<t1) mv2 = meta[(size_t)(t+2)*32 + (lane&31)];

        int d_ = mv.y;
        float w2v = __int_as_float(mv.z);

        bf16x8 A0lo,A0hi,A1lo,A1hi;
        {
            float w2a = __shfl(w2v, nn, 64);
            float w2b = __shfl(w2v, 16+nn, 64);
            #pragma unroll
            for(int j=0;j<8;++j){
                A0lo[j]=(__bf16)silu_f((float)gx0lo[j] + (float)gy0lo[j] + w2a*w128lo[j]);
                A0hi[j]=(__bf16)silu_f((float)gx0hi[j] + (float)gy0hi[j] + w2a*w128hi[j]);
                A1lo[j]=(__bf16)silu_f((float)gx1lo[j] + (float)gy1lo[j] + w2b*w128lo[j]);
                A1hi[j]=(__bf16)silu_f((float)gx1hi[j] + (float)gy1hi[j] + w2b*w128hi[j]);
            }
        }
        if(t+1<t1){
            int se0=__shfl(mvn.x, nn,64),    de0=__shfl(mvn.y, nn,64);
            int se1=__shfl(mvn.x, 16+nn,64), de1=__shfl(mvn.y, 16+nn,64);
            const __bf16* xp0=XY+(size_t)se0*128; const __bf16* yp0=XY+(size_t)de0*128+64;
            const __bf16* xp1=XY+(size_t)se1*128; const __bf16* yp1=XY+(size_t)de1*128+64;
            gx0lo=*(const bf16x8*)(xp0+8*q); gx0hi=*(const bf16x8*)(xp0+32+8*q);
            gy0lo=*(const bf16x8*)(yp0+8*q); gy0hi=*(const bf16x8*)(yp0+32+8*q);
            gx1lo=*(const bf16x8*)(xp1+8*q); gx1hi=*(const bf16x8*)(xp1+32+8*q);
            gy1lo=*(const bf16x8*)(yp1+8*q); gy1hi=*(const bf16x8*)(yp1+32+8*q);
        }
        #pragma unroll
        for(int h=0;h<2;++h){
            bf16x8 alo = h ? A1lo : A0lo;
            bf16x8 ahi = h ? A1hi : A0hi;
            f32x4 acc2[4];
            #pragma unroll
            for(int ng=0;ng<4;++ng){ f32x4 c; c[0]=bias2[ng]; c[1]=bias2[ng]; c[2]=bias2[ng]; c[3]=bias2[ng]; acc2[ng]=c; }
            #pragma unroll
            for(int ng=0;ng<4;++ng){
                acc2[ng]=__builtin_amdgcn_mfma_f32_16x16x32_bf16(alo,B2f[0][ng],acc2[ng],0,0,0);
                acc2[ng]=__builtin_amdgcn_mfma_f32_16x16x32_bf16(ahi,B2f[1][ng],acc2[ng],0,0,0);
            }
            #pragma unroll
            for(int r=0;r<4;++r){
                bf16x4 pv;
                #pragma unroll
                for(int ng=0;ng<4;++ng) pv[ng]=(__bf16)silu_f(silu_f(acc2[ng][r]));
                *(bf16x4*)&sm16[wid][16*h+4*q+r][4*nn] = pv;
            }
        }
        asm volatile("" ::: "memory");
        {
            int dprev = __shfl(d_, (lane+63)&63, 64);
            unsigned long long bal = __ballot(lane>=1 && lane<32 && d_!=dprev);
            unsigned bmask = (unsigned)bal;
            int d0 = __builtin_amdgcn_readlane(d_, 0);
            if(d0 != cur) bmask |= 1u;
            #pragma unroll
            for(int r=0;r<32;++r){
                if(bmask & (1u<<r)){
                    atomicAdd(&msum[(size_t)cur*64+lane], vsum);
                    vsum=0.f;
                    cur=__builtin_amdgcn_readlane(d_, r);
                }
                vsum += (float)sm16[wid][r][cpos];
            }
        }
        asm volatile("" ::: "memory");
        mv = mvn; mvn = mv2;
    }
    atomicAdd(&msum[(size_t)cur*64+lane], vsum);
}

// node 2-layer MLP via MFMA with optional fused next-layer XY (unchanged)
__global__ __launch_bounds__(256) void node_mfma(float* A, const float* F,
        const __bf16* __restrict__ pkW1, const float* __restrict__ b1,
        const __bf16* __restrict__ pkW2, const float* __restrict__ b2,
        float* __restrict__ out, int zeroA,
        const __bf16* __restrict__ pkXYa, const __bf16* __restrict__ pkXYb,
        const float* __restrict__ bXY, __bf16* __restrict__ XYout, int N){
    int tid=threadIdx.x, wid=tid>>6, lane=tid&63;
    int q=lane>>4, nn=lane&15;

    bf16x8 B1f[2][4], B2f[2][4];
    #pragma unroll
    for(int s=0;s<2;++s)
        #pragma unroll
        for(int ng=0;ng<4;++ng){ B1f[s][ng]=ldfrag(pkW1,s,ng,lane); B2f[s][ng]=ldfrag(pkW2,s,ng,lane); }
    float bias1[4], bias2[4];
    #pragma unroll
    for(int ng=0;ng<4;++ng){ bias1[ng]=b1[16*ng+nn]; bias2[ng]=b2[16*ng+nn]; }
    bool hasXY = (pkXYa != nullptr);
    float bXYv[4];
    #pragma unroll
    for(int j=0;j<4;++j) bXYv[j] = hasXY ? bXY[16*j+nn] : 0.f;

    __shared__ __align__(16) __bf16 sh1[4][16][72];
    __shared__ __align__(16) float sF[4][16][68];
    bool hasF = (F != nullptr);

    int ntiles=(N+15)/16;
    int gw=gridDim.x*4;
    for(int t=blockIdx.x*4+wid; t<ntiles; t+=gw){
        int m=t*16+nn;
        int mc=(m<N)?m:(N-1);
        float4 a0=*(const float4*)&A[(size_t)mc*64 + 8*q];
        float4 a1=*(const float4*)&A[(size_t)mc*64 + 8*q + 4];
        float4 a2=*(const float4*)&A[(size_t)mc*64 + 32 + 8*q];
        float4 a3=*(const float4*)&A[(size_t)mc*64 + 32 + 8*q + 4];
        if(hasF){
            float4 f0=*(const float4*)&F[(size_t)mc*64 + 8*q];
            float4 f1=*(const float4*)&F[(size_t)mc*64 + 8*q + 4];
            float4 f2_=*(const float4*)&F[(size_t)mc*64 + 32 + 8*q];
            float4 f3=*(const float4*)&F[(size_t)mc*64 + 32 + 8*q + 4];
            a0.x+=f0.x; a0.y+=f0.y; a0.z+=f0.z; a0.w+=f0.w;
            a1.x+=f1.x; a1.y+=f1.y; a1.z+=f1.z; a1.w+=f1.w;
            a2.x+=f2_.x; a2.y+=f2_.y; a2.z+=f2_.z; a2.w+=f2_.w;
            a3.x+=f3.x; a3.y+=f3.y; a3.z+=f3.z; a3.w+=f3.w;
            *(float4*)&sF[wid][nn][8*q]   = f0;
            *(float4*)&sF[wid][nn][8*q+4] = f1;
            *(float4*)&sF[wid][nn][32+8*q]   = f2_;
            *(float4*)&sF[wid][nn][32+8*q+4] = f3;
        }
        if(zeroA && m<N){
            float4 z; z.x=0.f; z.y=0.f; z.z=0.f; z.w=0.f;
            *(float4*)&A[(size_t)mc*64 + 8*q]      = z;
            *(float4*)&A[(size_t)mc*64 + 8*q + 4]  = z;
            *(float4*)&A[(size_t)mc*64 + 32 + 8*q] = z;
            *(float4*)&A[(size_t)mc*64 + 32 + 8*q + 4] = z;
        }
        bf16x8 af0, af1;
        af0[0]=(__bf16)a0.x; af0[1]=(__bf16)a0.y; af0[2]=(__bf16)a0.z; af0[3]=(__bf16)a0.w;
        af0[4]=(__bf16)a1.x; af0[5]=(__bf16)a1.y; af0[6]=(__bf16)a1.z; af0[7]=(__bf16)a1.w;
        af1[0]=(__bf16)a2.x; af1[1]=(__bf16)a2.y; af1[2]=(__bf16)a2.z; af1[3]=(__bf16)a2.w;
        af1[4]=(__bf16)a3.x; af1[5]=(__bf16)a3.y; af1[6]=(__bf16)a3.z; af1[7]=(__bf16)a3.w;

        f32x4 acc[4];
        #pragma unroll
        for(int ng=0;ng<4;++ng){ f32x4 c; c[0]=bias1[ng]; c[1]=bias1[ng]; c[2]=bias1[ng]; c[3]=bias1[ng]; acc[ng]=c; }
        #pragma unroll
        for(int ng=0;ng<4;++ng){
            acc[ng]=__builtin_amdgcn_mfma_f32_16x16x32_bf16(af0,B1f[0][ng],acc[ng],0,0,0);
            acc[ng]=__builtin_amdgcn_mfma_f32_16x16x32_bf16(af1,B1f[1][ng],acc[ng],0,0,0);
        }
        #pragma unroll
        for(int ng=0;ng<4;++ng)
            #pragma unroll
            for(int r=0;r<4;++r)
                sh1[wid][4*q+r][16*ng+nn]=(__bf16)silu_f(acc[ng][r]);
        asm volatile("" ::: "memory");
        bf16x8 a20=*(const bf16x8*)&sh1[wid][nn][8*q];
        bf16x8 a21=*(const bf16x8*)&sh1[wid][nn][32+8*q];
        f32x4 acc2[4];
        #pragma unroll
        for(int ng=0;ng<4;++ng){ f32x4 c; c[0]=bias2[ng]; c[1]=bias2[ng]; c[2]=bias2[ng]; c[3]=bias2[ng]; acc2[ng]=c; }
        #pragma unroll
        for(int ng=0;ng<4;++ng){
            acc2[ng]=__builtin_amdgcn_mfma_f32_16x16x32_bf16(a20,B2f[0][ng],acc2[ng],0,0,0);
            acc2[ng]=__builtin_amdgcn_mfma_f32_16x16x32_bf16(a21,B2f[1][ng],acc2[ng],0,0,0);
        }
        #pragma unroll
        for(int ng=0;ng<4;++ng)
            #pragma unroll
            for(int r=0;r<4;++r){
                int row=t*16+4*q+r;
                float o=acc2[ng][r];
                if(hasF) o += sF[wid][4*q+r][16*ng+nn];
                if(row<N) out[(size_t)row*64 + 16*ng + nn]=o;
                if(hasXY) sh1[wid][4*q+r][16*ng+nn]=(__bf16)o;
            }
        asm volatile("" ::: "memory");
        if(hasXY){
            bf16x8 a30=*(const bf16x8*)&sh1[wid][nn][8*q];
            bf16x8 a31=*(const bf16x8*)&sh1[wid][nn][32+8*q];
            #pragma unroll
            for(int ng=0;ng<8;++ng){
                const __bf16* pkx = (ng<4)? pkXYa : pkXYb;
                int g2 = ng&3;
                float bb = (ng<4)?0.f:bXYv[ng-4];
                f32x4 accx; accx[0]=bb; accx[1]=bb; accx[2]=bb; accx[3]=bb;
                accx=__builtin_amdgcn_mfma_f32_16x16x32_bf16(a30,ldfrag(pkx,0,g2,lane),accx,0,0,0);
                accx=__builtin_amdgcn_mfma_f32_16x16x32_bf16(a31,ldfrag(pkx,1,g2,lane),accx,0,0,0);
                #pragma unroll
                for(int r=0;r<4;++r){
                    int row=t*16+4*q+r;
                    if(row<N) XYout[(size_t)row*128 + 16*ng + nn]=(__bf16)accx[r];
                }
            }
        }
        asm volatile("" ::: "memory");
    }
}

// segment reduce over graphs (sorted gid, 1024 waves, atomic flush at boundaries)
__global__ __launch_bounds__(256) void seg_reduce_sorted(const float* __restrict__ f2, const int* __restrict__ gid,
        float* __restrict__ gsum, unsigned* __restrict__ gmaxu, float* __restrict__ cnt, int N){
    int wgl=blockIdx.x*4 + (threadIdx.x>>6);
    int lane=threadIdx.x&63;
    int W=gridDim.x*4;
    int chunk=(N+W-1)/W;
    int n0=wgl*chunk;
    int n1=n0+chunk; if(n1>N) n1=N;
    if(n0>=n1) return;
    int cur=gid[n0];
    float s=0.f, mx=-__builtin_inff(), c=0.f;
    for(int n=n0;n<n1;++n){
        int g=gid[n];
        float v=f2[(size_t)n*64+lane];
        if(g!=cur){
            atomicAdd(&gsum[(size_t)cur*64+lane], s);
            atomicMax(&gmaxu[(size_t)cur*64+lane], fenc(mx));
            if(lane==0) atomicAdd(&cnt[cur], c);
            s=0.f; mx=-__builtin_inff(); c=0.f; cur=g;
        }
        s+=v; mx=fmaxf(mx,v); c+=1.f;
    }
    atomicAdd(&gsum[(size_t)cur*64+lane], s);
    atomicMax(&gmaxu[(size_t)cur*64+lane], fenc(mx));
    if(lane==0) atomicAdd(&cnt[cur], c);
}

__global__ __launch_bounds__(256) void readout_k(const float* __restrict__ gsum, const unsigned* __restrict__ gmaxu,
        const float* __restrict__ cnt,
        const float* __restrict__ W1, const float* __restrict__ b1,
        const float* __restrict__ W2, const float* __restrict__ b2,
        float* __restrict__ out, int G){
    __shared__ __align__(16) float sr[4][192];
    int tid=threadIdx.x, wid=tid>>6, lane=tid&63;
    int g=blockIdx.x*4+wid;
    if(g<G){
        float s_=gsum[g*64+lane];
        float c=cnt[g];
        float mean=s_/fmaxf(c,1.0f);
        float mx=fdec(gmaxu[g*64+lane]);
        sr[wid][lane]=s_; sr[wid][64+lane]=mean; sr[wid][128+lane]=mx;
    }
    __syncthreads();
    if(g<G){
        float h=b1[lane];
        for(int k=0;k<192;k+=4){
            float4 r4=*(const float4*)&sr[wid][k];
            h += r4.x*W1[(k+0)*64+lane] + r4.y*W1[(k+1)*64+lane]
               + r4.z*W1[(k+2)*64+lane] + r4.w*W1[(k+3)*64+lane];
        }
        h=silu_f(h);
        float p=h*W2[lane];
        #pragma unroll
        for(int off=32;off>0;off>>=1) p += __shfl_down(p, off, 64);
        if(lane==0) out[g]=p+b2[0];
    }
}

extern "C" void kernel_launch(void* const* d_in, const int* in_sizes, int n_in,
                              void* d_out, int out_size, void* d_ws, size_t ws_size,
                              hipStream_t stream){
    const float* x     = (const float*)d_in[0];
    const float* w     = (const float*)d_in[1];
    const int*   src   = (const int*)d_in[2];
    const int*   dst   = (const int*)d_in[3];
    const int*   gid   = (const int*)d_in[4];
    const float* W_in  = (const float*)d_in[5];
    const float* b_in  = (const float*)d_in[6];
    const float* msgW1 = (const float*)d_in[7];
    const float* msgb1 = (const float*)d_in[8];
    const float* msgW2 = (const float*)d_in[9];
    const float* msgb2 = (const float*)d_in[10];
    const float* updW1 = (const float*)d_in[11];
    const float* updb1 = (const float*)d_in[12];
    const float* updW2 = (const float*)d_in[13];
    const float* updb2 = (const float*)d_in[14];
    const float* outW1 = (const float*)d_in[15];
    const float* outb1 = (const float*)d_in[16];
    const float* outW2 = (const float*)d_in[17];
    const float* outb2 = (const float*)d_in[18];
    const float* roW1  = (const float*)d_in[19];
    const float* rob1  = (const float*)d_in[20];
    const float* roW2  = (const float*)d_in[21];
    const float* rob2  = (const float*)d_in[22];

    float*  f     = (float*)d_ws;                         // N*64 f32
    float*  msum  = f + (size_t)NN*64;                    // N*64 f32 (reused as f2)
    float*  f2    = msum;
    __bf16* XY    = (__bf16*)(msum + (size_t)NN*64);      // N*128 bf16
    int4*   meta  = (int4*)(XY + (size_t)NN*128);         // E (16B each)
    __bf16* pk    = (__bf16*)(meta + EE);                 // 23*4096 bf16
    int*    deg   = (int*)(pk + 23*4096);                 // N (padded)
    int*    curs  = deg + 50048;                          // N (padded)
    int*    bsum  = curs + 50048;                         // SCAN_B (padded 256)
    float*  gsum  = (float*)(bsum + 256);                 // G*64
    unsigned* gmaxu = (unsigned*)(gsum + GG*64);          // G*64
    float*  cnt   = (float*)(gmaxu + GG*64);              // G

    pack_k<<<dim3(23),dim3(256),0,stream>>>(msgW1, msgW2, updW1, updW2, outW1, outW2, W_in, pk);

    hipMemsetAsync(deg, 0, 50048*sizeof(int), stream);
    hist_k<<<dim3((EE+255)/256),dim3(256),0,stream>>>(dst, deg, EE);
    scan1_k<<<dim3(SCAN_B),dim3(256),0,stream>>>(deg, curs, bsum, NN);
    scan2_k<<<dim3(1),dim3(256),0,stream>>>(bsum, SCAN_B);
    scan3_k<<<dim3(SCAN_B),dim3(256),0,stream>>>(curs, bsum, NN);
    fill_k<<<dim3((EE+255)/256),dim3(256),0,stream>>>(src, dst, w, curs, meta, EE);

    // msum zeroed once here; node_mfma (zeroA=1) re-zeros it for each subsequent layer
    hipMemsetAsync(msum, 0, (size_t)NN*64*sizeof(float), stream);
    input_mfma<<<dim3(782),dim3(256),0,stream>>>(x, pk + (size_t)22*4096, b_in,
        pk + (size_t)0*4096, pk + (size_t)1*4096, msgb1 + 0*64, f, XY, NN);
    for(int l=0;l<LL;++l){
        edge_mfma6<<<dim3(1280),dim3(256),0,stream>>>(XY, meta,
            pk + (size_t)(5*l+2)*4096,
            msgW1 + (size_t)l*129*64, msgb2 + l*64, msum, EE);
        bool fuse = (l < LL-1);
        node_mfma<<<dim3(782),dim3(256),0,stream>>>(msum, f,
            pk + (size_t)(5*l+3)*4096, updb1 + l*64,
            pk + (size_t)(5*l+4)*4096, updb2 + l*64, f, 1,
            fuse ? pk + (size_t)(5*(l+1)+0)*4096 : nullptr,
            fuse ? pk + (size_t)(5*(l+1)+1)*4096 : nullptr,
            fuse ? msgb1 + (l+1)*64 : nullptr,
            XY, NN);
    }
    node_mfma<<<dim3(782),dim3(256),0,stream>>>(f, nullptr,
        pk + (size_t)20*4096, outb1, pk + (size_t)21*4096, outb2, f2, 0,
        nullptr, nullptr, nullptr, nullptr, NN);
    hipMemsetAsync(gsum, 0, (size_t)(GG*64*2 + GG)*sizeof(float), stream);
    seg_reduce_sorted<<<dim3(256),dim3(256),0,stream>>>(f2, gid, gsum, gmaxu, cnt, NN);
    readout_k<<<dim3(32),dim3(256),0,stream>>>(gsum, gmaxu, cnt, roW1, rob1, roW2, rob2, (float*)d_out, GG);
}